// Round 1
// baseline (936.564 us; speedup 1.0000x reference)
//
#include <hip/hip_runtime.h>
#include <hip/hip_bf16.h>
#include <stdint.h>

// Shapes (fixed by the problem): b=2, n=5, k=5, q=75, t=196, c=384, s=k*t=980
// Outputs: logits [2,75,5] (750 floats) then cls_logits [2,75,5] (750 floats)

typedef __attribute__((ext_vector_type(8))) short short8;   // 8 bf16 = 4 VGPRs (MFMA A/B frag)
typedef __attribute__((ext_vector_type(4))) float f32x4;    // MFMA C/D frag

// ---------------- normalization: one wave per 384-elem token ----------------
__global__ void norm_kernel(const float* __restrict__ in, __hip_bfloat16* __restrict__ out,
                            int ntok, float eps) {
    const int gw   = (blockIdx.x * 256 + threadIdx.x) >> 6;
    const int lane = threadIdx.x & 63;
    if (gw >= ntok) return;
    const float* row = in + (size_t)gw * 384;
    float v[6];
    float ss = 0.f;
#pragma unroll
    for (int j = 0; j < 6; ++j) { v[j] = row[lane + 64 * j]; ss += v[j] * v[j]; }
#pragma unroll
    for (int off = 1; off < 64; off <<= 1) ss += __shfl_xor(ss, off, 64);
    const float scale = 1.0f / fmaxf(sqrtf(ss), eps);
    __hip_bfloat16* orow = out + (size_t)gw * 384;
#pragma unroll
    for (int j = 0; j < 6; ++j) orow[lane + 64 * j] = __float2bfloat16(v[j] * scale);
}

// ---------------- proto = l2norm(mean_k x_shot): one wave per (b,n) ----------------
__global__ void proto_kernel(const float* __restrict__ xs, float* __restrict__ proto) {
    const int gw   = (blockIdx.x * 256 + threadIdx.x) >> 6;  // 0..9 = b*5+n
    const int lane = threadIdx.x & 63;
    if (gw >= 10) return;
    const float* base = xs + (size_t)gw * 5 * 384;  // [k=5][c=384]
    float v[6];
    float ss = 0.f;
#pragma unroll
    for (int j = 0; j < 6; ++j) {
        float s = 0.f;
#pragma unroll
        for (int kk = 0; kk < 5; ++kk) s += base[kk * 384 + lane + 64 * j];
        s *= 0.2f;
        v[j] = s;
        ss += s * s;
    }
#pragma unroll
    for (int off = 1; off < 64; off <<= 1) ss += __shfl_xor(ss, off, 64);
    const float scale = 1.0f / fmaxf(sqrtf(ss), 1e-12f);
#pragma unroll
    for (int j = 0; j < 6; ++j) proto[(size_t)gw * 384 + lane + 64 * j] = v[j] * scale;
}

// ---------------- cls_logits = 10 * <l2norm(xq), proto>: one wave per (b,q) ----------------
__global__ void cls_kernel(const float* __restrict__ xq, const float* __restrict__ proto,
                           float* __restrict__ out) {
    const int gw   = (blockIdx.x * 256 + threadIdx.x) >> 6;  // 0..149 = b*75+q
    const int lane = threadIdx.x & 63;
    if (gw >= 150) return;
    const float* row = xq + (size_t)gw * 384;
    float u[6];
    float ss = 0.f;
#pragma unroll
    for (int j = 0; j < 6; ++j) { u[j] = row[lane + 64 * j]; ss += u[j] * u[j]; }
#pragma unroll
    for (int off = 1; off < 64; off <<= 1) ss += __shfl_xor(ss, off, 64);
    const float scale = 1.0f / fmaxf(sqrtf(ss), 1e-12f);
#pragma unroll
    for (int j = 0; j < 6; ++j) u[j] *= scale;
    const int b = gw / 75;
    for (int n = 0; n < 5; ++n) {
        const float* p = proto + (size_t)(b * 5 + n) * 384;
        float d = 0.f;
#pragma unroll
        for (int j = 0; j < 6; ++j) d += u[j] * p[lane + 64 * j];
#pragma unroll
        for (int off = 1; off < 64; off <<= 1) d += __shfl_xor(d, off, 64);
        if (lane == 0) out[750 + gw * 5 + n] = 10.0f * d;
    }
}

// ---------------- main kernel: per (b,q,n): rowmax_s(Fq·Fs^T) then mean_t ----------------
// Block = 256 threads (4 waves). M=196 (13 x 16-row MFMA tiles, padded to 208),
// S=980 in 16 chunks of 64 (one 16-col n-tile per wave), K=384 in 6 chunks of 64 via LDS.
__global__ __launch_bounds__(256) void sim_kernel(const uint16_t* __restrict__ fqn,
                                                  const uint16_t* __restrict__ fsn,
                                                  float* __restrict__ out) {
    __shared__ uint16_t Alds[208 * 64];   // 26.0 KB
    __shared__ uint16_t Blds[64 * 64];    //  8.0 KB
    __shared__ float red[4 * 208];        //  3.3 KB (per-wave row maxima)
    __shared__ float part[4];

    const int bid = blockIdx.x;       // ((b*75+q)*5+n)
    const int n   = bid % 5;
    const int bq  = bid / 5;          // b*75+q
    const int b   = bq / 75;

    const uint16_t* Ag = fqn + (size_t)bq * (196 * 384);
    const uint16_t* Bg = fsn + (size_t)(b * 5 + n) * (980 * 384);

    const int tid  = threadIdx.x;
    const int lane = tid & 63;
    const int wv   = tid >> 6;
    const int l15  = lane & 15;
    const int hi   = lane >> 4;

    float rowmax[13][4];
#pragma unroll
    for (int mt = 0; mt < 13; ++mt)
#pragma unroll
        for (int i = 0; i < 4; ++i) rowmax[mt][i] = -3.0e38f;

    for (int sc = 0; sc < 16; ++sc) {
        const int s_base = sc * 64;
        f32x4 acc[13];
#pragma unroll
        for (int mt = 0; mt < 13; ++mt) acc[mt] = (f32x4){0.f, 0.f, 0.f, 0.f};

        for (int kc = 0; kc < 6; ++kc) {
            __syncthreads();
            // stage A tile [208 x 64] bf16 (rows >=196 zero)
            for (int g = tid; g < 1664; g += 256) {   // 1664 = 208*64/8
                const int row = g >> 3;
                const int col = (g & 7) * 8;
                uint4 val = make_uint4(0u, 0u, 0u, 0u);
                if (row < 196) val = *(const uint4*)(Ag + (size_t)row * 384 + kc * 64 + col);
                *(uint4*)(&Alds[row * 64 + col]) = val;
            }
            // stage B tile [64 x 64] bf16 (rows with s>=980 zero)
            for (int g = tid; g < 512; g += 256) {    // 512 = 64*64/8
                const int row = g >> 3;
                const int col = (g & 7) * 8;
                const int s = s_base + row;
                uint4 val = make_uint4(0u, 0u, 0u, 0u);
                if (s < 980) val = *(const uint4*)(Bg + (size_t)s * 384 + kc * 64 + col);
                *(uint4*)(&Blds[row * 64 + col]) = val;
            }
            __syncthreads();
#pragma unroll
            for (int ks = 0; ks < 2; ++ks) {
                const short8 bf = *(const short8*)(&Blds[(wv * 16 + l15) * 64 + ks * 32 + hi * 8]);
#pragma unroll
                for (int mt = 0; mt < 13; ++mt) {
                    const short8 af = *(const short8*)(&Alds[(mt * 16 + l15) * 64 + ks * 32 + hi * 8]);
                    acc[mt] = __builtin_amdgcn_mfma_f32_16x16x32_bf16(af, bf, acc[mt], 0, 0, 0);
                }
            }
        }
        // fold this s-chunk into running row maxima (lane's column = s_base + wv*16 + l15)
        const int s_col = s_base + wv * 16 + l15;
        if (s_col < 980) {
#pragma unroll
            for (int mt = 0; mt < 13; ++mt)
#pragma unroll
                for (int i = 0; i < 4; ++i) rowmax[mt][i] = fmaxf(rowmax[mt][i], acc[mt][i]);
        }
    }

    // max across the 16 column-lanes (xor over bits 0..3 stays within the 16-group)
#pragma unroll
    for (int mt = 0; mt < 13; ++mt)
#pragma unroll
        for (int i = 0; i < 4; ++i) {
            float v = rowmax[mt][i];
#pragma unroll
            for (int off = 1; off < 16; off <<= 1) v = fmaxf(v, __shfl_xor(v, off, 64));
            rowmax[mt][i] = v;
        }

    // lane l15==0 of each hi-group writes its 4 rows per m-tile
    if (l15 == 0) {
#pragma unroll
        for (int mt = 0; mt < 13; ++mt)
#pragma unroll
            for (int i = 0; i < 4; ++i)
                red[wv * 208 + mt * 16 + hi * 4 + i] = rowmax[mt][i];
    }
    __syncthreads();

    // combine 4 waves' maxima, mean over the 196 valid rows
    float v = 0.0f;
    if (tid < 196)
        v = fmaxf(fmaxf(red[tid], red[208 + tid]), fmaxf(red[416 + tid], red[624 + tid]));
#pragma unroll
    for (int off = 1; off < 64; off <<= 1) v += __shfl_xor(v, off, 64);
    if (lane == 0) part[wv] = v;
    __syncthreads();
    if (tid == 0) out[bid] = (part[0] + part[1] + part[2] + part[3]) * (1.0f / 196.0f);
}

extern "C" void kernel_launch(void* const* d_in, const int* in_sizes, int n_in,
                              void* d_out, int out_size, void* d_ws, size_t ws_size,
                              hipStream_t stream) {
    const float* feat_shot  = (const float*)d_in[0];  // [2,5,5,196,384]
    const float* feat_query = (const float*)d_in[1];  // [2,75,196,384]
    const float* x_shot     = (const float*)d_in[2];  // [2,5,5,384]
    const float* x_query    = (const float*)d_in[3];  // [2,75,384]
    float* out = (float*)d_out;
    char* ws = (char*)d_ws;

    // workspace layout (30.12 MB total)
    __hip_bfloat16* fqn = (__hip_bfloat16*)ws;                        // 11,289,600 bf16
    __hip_bfloat16* fsn = (__hip_bfloat16*)(ws + 22579200);           //  3,763,200 bf16
    float*        proto = (float*)(ws + 22579200 + 7526400);          //      3,840 f32

    const int ntok_q = 2 * 75 * 196;      // 29400
    const int ntok_s = 2 * 5 * 5 * 196;   //  9800

    norm_kernel<<<(ntok_q + 3) / 4, 256, 0, stream>>>(feat_query, fqn, ntok_q, 1e-8f);
    norm_kernel<<<(ntok_s + 3) / 4, 256, 0, stream>>>(feat_shot, fsn, ntok_s, 1e-8f);
    proto_kernel<<<3, 256, 0, stream>>>(x_shot, proto);
    cls_kernel<<<38, 256, 0, stream>>>(x_query, proto, out);
    sim_kernel<<<750, 256, 0, stream>>>((const uint16_t*)fqn, (const uint16_t*)fsn, out);
}

// Round 2
// 298.993 us; speedup vs baseline: 3.1324x; 3.1324x over previous
//
#include <hip/hip_runtime.h>
#include <hip/hip_bf16.h>
#include <stdint.h>

// Shapes: b=2, n=5, k=5, q=75, t=196, c=384, s=k*t=980 (padded to 1024/class)
// M per b = 75*196 = 14700 (padded to 14720 = 115 tiles of 128)
// Outputs: logits [2,75,5] then cls_logits [2,75,5]

typedef __attribute__((ext_vector_type(8))) short short8;   // MFMA A/B frag (8 bf16)
typedef __attribute__((ext_vector_type(4))) float f32x4;    // MFMA C/D frag

__device__ __forceinline__ void load_lds16(const void* g, void* l) {
    __builtin_amdgcn_global_load_lds(
        (const __attribute__((address_space(1))) unsigned int*)(uintptr_t)g,
        (__attribute__((address_space(3))) unsigned int*)(uintptr_t)l,
        16, 0, 0);
}

__device__ __forceinline__ unsigned enc_f(float f) {
    unsigned b = __float_as_uint(f);
    return (b & 0x80000000u) ? ~b : (b | 0x80000000u);
}
__device__ __forceinline__ float dec_f(unsigned u) {
    unsigned b = (u & 0x80000000u) ? (u & 0x7FFFFFFFu) : ~u;
    return __uint_as_float(b);
}

// ---------------- query norm: one wave per token, natural layout ----------------
__global__ void norm_q_kernel(const float* __restrict__ in, __hip_bfloat16* __restrict__ out,
                              int ntok) {
    const int gw   = (blockIdx.x * 256 + threadIdx.x) >> 6;
    const int lane = threadIdx.x & 63;
    if (gw >= ntok) return;
    const float* row = in + (size_t)gw * 384;
    float v[6];
    float ss = 0.f;
#pragma unroll
    for (int j = 0; j < 6; ++j) { v[j] = row[lane + 64 * j]; ss += v[j] * v[j]; }
#pragma unroll
    for (int off = 1; off < 64; off <<= 1) ss += __shfl_xor(ss, off, 64);
    const float scale = 1.0f / fmaxf(sqrtf(ss), 1e-8f);
    __hip_bfloat16* orow = out + (size_t)gw * 384;
#pragma unroll
    for (int j = 0; j < 6; ++j) orow[lane + 64 * j] = __float2bfloat16(v[j] * scale);
}

// ---------------- shot norm into padded layout [b*5+n][1024][384], pad rows = 0 ----------------
__global__ void norm_s_kernel(const float* __restrict__ in, __hip_bfloat16* __restrict__ out) {
    const int gw   = (blockIdx.x * 256 + threadIdx.x) >> 6;  // 0..10239
    const int lane = threadIdx.x & 63;
    if (gw >= 10240) return;
    const int bn = gw >> 10;          // b*5+n
    const int s  = gw & 1023;         // class-local padded row
    __hip_bfloat16* orow = out + (size_t)gw * 384;
    if (s >= 980) {
#pragma unroll
        for (int j = 0; j < 6; ++j) orow[lane + 64 * j] = __float2bfloat16(0.0f);
        return;
    }
    const float* row = in + ((size_t)bn * 980 + s) * 384;  // [b][n][k][t][c] flat
    float v[6];
    float ss = 0.f;
#pragma unroll
    for (int j = 0; j < 6; ++j) { v[j] = row[lane + 64 * j]; ss += v[j] * v[j]; }
#pragma unroll
    for (int off = 1; off < 64; off <<= 1) ss += __shfl_xor(ss, off, 64);
    const float scale = 1.0f / fmaxf(sqrtf(ss), 1e-8f);
#pragma unroll
    for (int j = 0; j < 6; ++j) orow[lane + 64 * j] = __float2bfloat16(v[j] * scale);
}

// ---------------- proto = l2norm(mean_k x_shot): one wave per (b,n) ----------------
__global__ void proto_kernel(const float* __restrict__ xs, float* __restrict__ proto) {
    const int gw   = (blockIdx.x * 256 + threadIdx.x) >> 6;
    const int lane = threadIdx.x & 63;
    if (gw >= 10) return;
    const float* base = xs + (size_t)gw * 5 * 384;
    float v[6];
    float ss = 0.f;
#pragma unroll
    for (int j = 0; j < 6; ++j) {
        float s = 0.f;
#pragma unroll
        for (int kk = 0; kk < 5; ++kk) s += base[kk * 384 + lane + 64 * j];
        s *= 0.2f;
        v[j] = s;
        ss += s * s;
    }
#pragma unroll
    for (int off = 1; off < 64; off <<= 1) ss += __shfl_xor(ss, off, 64);
    const float scale = 1.0f / fmaxf(sqrtf(ss), 1e-12f);
#pragma unroll
    for (int j = 0; j < 6; ++j) proto[(size_t)gw * 384 + lane + 64 * j] = v[j] * scale;
}

// ---------------- cls_logits = 10 * <l2norm(xq), proto>: one wave per (b,q) ----------------
__global__ void cls_kernel(const float* __restrict__ xq, const float* __restrict__ proto,
                           float* __restrict__ out) {
    const int gw   = (blockIdx.x * 256 + threadIdx.x) >> 6;
    const int lane = threadIdx.x & 63;
    if (gw >= 150) return;
    const float* row = xq + (size_t)gw * 384;
    float u[6];
    float ss = 0.f;
#pragma unroll
    for (int j = 0; j < 6; ++j) { u[j] = row[lane + 64 * j]; ss += u[j] * u[j]; }
#pragma unroll
    for (int off = 1; off < 64; off <<= 1) ss += __shfl_xor(ss, off, 64);
    const float scale = 1.0f / fmaxf(sqrtf(ss), 1e-12f);
#pragma unroll
    for (int j = 0; j < 6; ++j) u[j] *= scale;
    const int b = gw / 75;
    for (int n = 0; n < 5; ++n) {
        const float* p = proto + (size_t)(b * 5 + n) * 384;
        float d = 0.f;
#pragma unroll
        for (int j = 0; j < 6; ++j) d += u[j] * p[lane + 64 * j];
#pragma unroll
        for (int off = 1; off < 64; off <<= 1) d += __shfl_xor(d, off, 64);
        if (lane == 0) out[750 + gw * 5 + n] = 10.0f * d;
    }
}

// ---------------- init P (encoded row-max accumulator) to 0 = -inf ----------------
__global__ void init_p_kernel(unsigned* __restrict__ P) {
    const int i = blockIdx.x * 256 + threadIdx.x;
    if (i < 147000) P[i] = 0u;
}

// ---------------- batched GEMM + row-max: 128x128 tile, BK=64, m97 structure ----------------
// grid = 2 * 115 * 40; per block: C[128x128] = A[128x384] * B^T, fold max over cols.
__global__ __launch_bounds__(256) void gemm_kernel(const uint16_t* __restrict__ fqn,
                                                   const uint16_t* __restrict__ fsnp,
                                                   unsigned* __restrict__ P) {
    __shared__ uint16_t Atile[128 * 64];   // 16 KB
    __shared__ uint16_t Btile[128 * 64];   // 16 KB
    __shared__ float red[2][128];          // 1 KB

    const int bid = blockIdx.x;
    const int b   = bid / 4600;
    const int r   = bid % 4600;
    const int mt  = r / 40;
    const int st  = r % 40;
    const int m0  = mt * 128;          // row in [0,14720)
    const int s0  = st * 128;          // col in padded [0,5120)
    const int cls = s0 >> 10;          // class n
    const int s_loc = s0 & 1023;       // class-local col base

    const uint16_t* Ag = fqn  + (size_t)b * 14700 * 384;
    const uint16_t* Bg = fsnp + ((size_t)b * 5120 + s0) * 384;

    const int tid  = threadIdx.x;
    const int lane = tid & 63;
    const int wv   = tid >> 6;
    const int l15  = lane & 15;
    const int hi   = lane >> 4;
    const int m0w  = (wv & 1) * 64;
    const int n0w  = (wv >> 1) * 64;

    // staging coords for this thread (4 granules of 16B per tile)
    const int g_row = tid >> 3;        // 0..31 (+32 per iter)
    const int g_col = (tid & 7) * 8;   // bf16 elem col

    f32x4 acc[4][4];
#pragma unroll
    for (int mi = 0; mi < 4; ++mi)
#pragma unroll
        for (int ni = 0; ni < 4; ++ni) acc[mi][ni] = (f32x4){0.f, 0.f, 0.f, 0.f};

    for (int kc = 0; kc < 6; ++kc) {
        __syncthreads();
#pragma unroll
        for (int i = 0; i < 4; ++i) {
            const int row = i * 32 + g_row;
            // A tile: guard rows beyond 14700 (stale LDS there only affects dead rows)
            if (m0 + row < 14700)
                load_lds16(Ag + (size_t)(m0 + row) * 384 + kc * 64 + g_col,
                           &Atile[(i * 256 + wv * 64) * 8]);
            // B tile: padded buffer, always valid
            load_lds16(Bg + (size_t)row * 384 + kc * 64 + g_col,
                       &Btile[(i * 256 + wv * 64) * 8]);
        }
        __syncthreads();
#pragma unroll
        for (int ks = 0; ks < 2; ++ks) {
            short8 af[4], bf[4];
#pragma unroll
            for (int mi = 0; mi < 4; ++mi)
                af[mi] = *(const short8*)(&Atile[(m0w + mi * 16 + l15) * 64 + ks * 32 + hi * 8]);
#pragma unroll
            for (int ni = 0; ni < 4; ++ni)
                bf[ni] = *(const short8*)(&Btile[(n0w + ni * 16 + l15) * 64 + ks * 32 + hi * 8]);
#pragma unroll
            for (int mi = 0; mi < 4; ++mi)
#pragma unroll
                for (int ni = 0; ni < 4; ++ni)
                    acc[mi][ni] = __builtin_amdgcn_mfma_f32_16x16x32_bf16(af[mi], bf[ni], acc[mi][ni], 0, 0, 0);
        }
    }

    // ---- epilogue: per-row max over this block's 128 cols (masked at class boundary) ----
    float rmax[4][4];
#pragma unroll
    for (int mi = 0; mi < 4; ++mi)
#pragma unroll
        for (int i = 0; i < 4; ++i) rmax[mi][i] = -3.0e38f;

    const int scol = s_loc + n0w + l15;   // this lane's class-local col (+ ni*16)
#pragma unroll
    for (int ni = 0; ni < 4; ++ni) {
        if (scol + ni * 16 < 980) {
#pragma unroll
            for (int mi = 0; mi < 4; ++mi)
#pragma unroll
                for (int i = 0; i < 4; ++i)
                    rmax[mi][i] = fmaxf(rmax[mi][i], acc[mi][ni][i]);
        }
    }
    // max across the 16 column-lanes
#pragma unroll
    for (int mi = 0; mi < 4; ++mi)
#pragma unroll
        for (int i = 0; i < 4; ++i) {
            float v = rmax[mi][i];
#pragma unroll
            for (int off = 1; off < 16; off <<= 1) v = fmaxf(v, __shfl_xor(v, off, 64));
            rmax[mi][i] = v;
        }
    if (l15 == 0) {
#pragma unroll
        for (int mi = 0; mi < 4; ++mi)
#pragma unroll
            for (int i = 0; i < 4; ++i)
                red[wv >> 1][m0w + mi * 16 + hi * 4 + i] = rmax[mi][i];
    }
    __syncthreads();
    if (tid < 128) {
        const int grow = m0 + tid;
        if (grow < 14700) {
            const float v = fmaxf(red[0][tid], red[1][tid]);
            atomicMax(&P[(size_t)(b * 5 + cls) * 14700 + grow], enc_f(v));
        }
    }
}

// ---------------- logits = mean over t of decoded row maxima ----------------
__global__ void logits_kernel(const unsigned* __restrict__ P, float* __restrict__ out) {
    const int gw   = (blockIdx.x * 256 + threadIdx.x) >> 6;  // 0..749 = (b*75+q)*5+n
    const int lane = threadIdx.x & 63;
    if (gw >= 750) return;
    const int n  = gw % 5;
    const int bq = gw / 5;
    const int b  = bq / 75;
    const int q  = bq % 75;
    const unsigned* row = P + (size_t)(b * 5 + n) * 14700 + q * 196;
    float s = 0.f;
    for (int t = lane; t < 196; t += 64) s += dec_f(row[t]);
#pragma unroll
    for (int off = 1; off < 64; off <<= 1) s += __shfl_xor(s, off, 64);
    if (lane == 0) out[gw] = s * (1.0f / 196.0f);
}

extern "C" void kernel_launch(void* const* d_in, const int* in_sizes, int n_in,
                              void* d_out, int out_size, void* d_ws, size_t ws_size,
                              hipStream_t stream) {
    const float* feat_shot  = (const float*)d_in[0];  // [2,5,5,196,384]
    const float* feat_query = (const float*)d_in[1];  // [2,75,196,384]
    const float* x_shot     = (const float*)d_in[2];  // [2,5,5,384]
    const float* x_query    = (const float*)d_in[3];  // [2,75,384]
    float* out = (float*)d_out;
    char* ws = (char*)d_ws;

    // ws layout (29.6 MiB total)
    __hip_bfloat16* fqn  = (__hip_bfloat16*)ws;                      // 11,289,600 bf16 = 22,579,200 B
    __hip_bfloat16* fsnp = (__hip_bfloat16*)(ws + 22579200);         //  3,932,160 bf16 =  7,864,320 B
    float*         proto = (float*)(ws + 30443520);                  //      3,840 f32  =     15,360 B
    unsigned*      P     = (unsigned*)(ws + 30458880);               //    147,000 u32  =    588,000 B

    const int ntok_q = 2 * 75 * 196;   // 29400

    norm_q_kernel<<<(ntok_q + 3) / 4, 256, 0, stream>>>(feat_query, fqn, ntok_q);
    norm_s_kernel<<<2560, 256, 0, stream>>>(feat_shot, fsnp);
    proto_kernel<<<3, 256, 0, stream>>>(x_shot, proto);
    cls_kernel<<<38, 256, 0, stream>>>(x_query, proto, out);
    init_p_kernel<<<(147000 + 255) / 256, 256, 0, stream>>>(P);
    gemm_kernel<<<2 * 115 * 40, 256, 0, stream>>>((const uint16_t*)fqn, (const uint16_t*)fsnp, P);
    logits_kernel<<<(750 + 3) / 4, 256, 0, stream>>>(P, out);
}

// Round 3
// 254.004 us; speedup vs baseline: 3.6872x; 1.1771x over previous
//
#include <hip/hip_runtime.h>
#include <hip/hip_bf16.h>
#include <stdint.h>

// Shapes: b=2, n=5, k=5, q=75, t=196, c=384, s=k*t=980 (padded to 1024/class)
// M per b = 75*196 = 14700 (padded to 14720 = 115 tiles of 128)
// Outputs: logits [2,75,5] then cls_logits [2,75,5]

typedef __attribute__((ext_vector_type(8))) short short8;   // MFMA A/B frag (8 bf16)
typedef __attribute__((ext_vector_type(4))) float f32x4;    // MFMA C/D frag

__device__ __forceinline__ void load_lds16(const void* g, void* l) {
    __builtin_amdgcn_global_load_lds(
        (const __attribute__((address_space(1))) unsigned int*)(uintptr_t)g,
        (__attribute__((address_space(3))) unsigned int*)(uintptr_t)l,
        16, 0, 0);
}

__device__ __forceinline__ unsigned enc_f(float f) {
    unsigned b = __float_as_uint(f);
    return (b & 0x80000000u) ? ~b : (b | 0x80000000u);
}
__device__ __forceinline__ float dec_f(unsigned u) {
    unsigned b = (u & 0x80000000u) ? (u & 0x7FFFFFFFu) : ~u;
    return __uint_as_float(b);
}

// ---------------- fused prep: norm_q | norm_s(padded) | proto | init_P ----------------
// blocks [0,7350): query tokens (4/block); [7350,9910): shot tokens padded (4/block);
// [9910,9913): proto; [9913,10488): init P.
__global__ void prep_kernel(const float* __restrict__ feat_query,
                            const float* __restrict__ feat_shot,
                            const float* __restrict__ x_shot,
                            __hip_bfloat16* __restrict__ fqn,
                            __hip_bfloat16* __restrict__ fsnp,
                            float* __restrict__ proto,
                            unsigned* __restrict__ P) {
    const int blk  = blockIdx.x;
    const int tid  = threadIdx.x;
    const int lane = tid & 63;
    const int wv   = tid >> 6;

    if (blk < 7350) {                       // ---- query token L2 norm ----
        const int gw = blk * 4 + wv;        // 0..29399
        if (gw >= 29400) return;
        const float* row = feat_query + (size_t)gw * 384;
        float v[6];
        float ss = 0.f;
#pragma unroll
        for (int j = 0; j < 6; ++j) { v[j] = row[lane + 64 * j]; ss += v[j] * v[j]; }
#pragma unroll
        for (int off = 1; off < 64; off <<= 1) ss += __shfl_xor(ss, off, 64);
        const float scale = 1.0f / fmaxf(sqrtf(ss), 1e-8f);
        __hip_bfloat16* orow = fqn + (size_t)gw * 384;
#pragma unroll
        for (int j = 0; j < 6; ++j) orow[lane + 64 * j] = __float2bfloat16(v[j] * scale);
    } else if (blk < 9910) {                // ---- shot token L2 norm into padded layout ----
        const int gw = (blk - 7350) * 4 + wv;   // 0..10239
        if (gw >= 10240) return;
        const int bn = gw >> 10;
        const int s  = gw & 1023;
        __hip_bfloat16* orow = fsnp + (size_t)gw * 384;
        if (s >= 980) {
#pragma unroll
            for (int j = 0; j < 6; ++j) orow[lane + 64 * j] = __float2bfloat16(0.0f);
            return;
        }
        const float* row = feat_shot + ((size_t)bn * 980 + s) * 384;
        float v[6];
        float ss = 0.f;
#pragma unroll
        for (int j = 0; j < 6; ++j) { v[j] = row[lane + 64 * j]; ss += v[j] * v[j]; }
#pragma unroll
        for (int off = 1; off < 64; off <<= 1) ss += __shfl_xor(ss, off, 64);
        const float scale = 1.0f / fmaxf(sqrtf(ss), 1e-8f);
#pragma unroll
        for (int j = 0; j < 6; ++j) orow[lane + 64 * j] = __float2bfloat16(v[j] * scale);
    } else if (blk < 9913) {                // ---- proto = l2norm(mean_k x_shot) ----
        const int gw = (blk - 9910) * 4 + wv;   // 0..9 used
        if (gw >= 10) return;
        const float* base = x_shot + (size_t)gw * 5 * 384;
        float v[6];
        float ss = 0.f;
#pragma unroll
        for (int j = 0; j < 6; ++j) {
            float s = 0.f;
#pragma unroll
            for (int kk = 0; kk < 5; ++kk) s += base[kk * 384 + lane + 64 * j];
            s *= 0.2f;
            v[j] = s;
            ss += s * s;
        }
#pragma unroll
        for (int off = 1; off < 64; off <<= 1) ss += __shfl_xor(ss, off, 64);
        const float scale = 1.0f / fmaxf(sqrtf(ss), 1e-12f);
#pragma unroll
        for (int j = 0; j < 6; ++j) proto[(size_t)gw * 384 + lane + 64 * j] = v[j] * scale;
    } else {                                // ---- init P to encoded -inf (0) ----
        const int i = (blk - 9913) * 256 + tid;
        if (i < 147000) P[i] = 0u;
    }
}

// ---------------- batched GEMM + row-max: 128x128 tile, BK=64, XOR-swizzled LDS ----------------
// grid = 2 * 115 * 40. LDS granule (row r, slot g) holds global K-granule g ^ (r&7)
// (16B granules, 8 per 64-elem K-chunk). global_load_lds dest stays wave-uniform+lane*16;
// the swizzle is applied on the per-lane SOURCE address. Frag reads address granule
// (ks*4+hi) ^ (l15&7) -> bank quadrant uniform over all 8 -> minimal (8-lane) aliasing.
__global__ __launch_bounds__(256) void gemm_kernel(const uint16_t* __restrict__ fqn,
                                                   const uint16_t* __restrict__ fsnp,
                                                   unsigned* __restrict__ P) {
    __shared__ uint16_t Atile[128 * 64];   // 16 KB
    __shared__ uint16_t Btile[128 * 64];   // 16 KB
    __shared__ float red[2][128];          // 1 KB

    const int bid = blockIdx.x;
    const int b   = bid / 4600;
    const int r   = bid % 4600;
    const int mt  = r / 40;
    const int st  = r % 40;
    const int m0  = mt * 128;          // row in [0,14720)
    const int s0  = st * 128;          // col in padded [0,5120)
    const int cls = s0 >> 10;          // class n
    const int s_loc = s0 & 1023;       // class-local col base

    const uint16_t* Ag = fqn  + (size_t)b * 14700 * 384;
    const uint16_t* Bg = fsnp + ((size_t)b * 5120 + s0) * 384;

    const int tid  = threadIdx.x;
    const int lane = tid & 63;
    const int wv   = tid >> 6;
    const int l15  = lane & 15;
    const int hi   = lane >> 4;
    const int m0w  = (wv & 1) * 64;
    const int n0w  = (wv >> 1) * 64;
    const int swz  = l15 & 7;          // frag-read swizzle key (= row & 7)

    // staging coords: row = i*32 + (tid>>3), LDS slot granule = tid&7,
    // source granule = (tid&7) ^ (row&7) = (tid&7) ^ ((tid>>3)&7)  (i*32 is 0 mod 8)
    const int g_row  = tid >> 3;                       // 0..31
    const int src_g  = ((tid & 7) ^ (g_row & 7)) * 8;  // source elem offset in K-chunk

    f32x4 acc[4][4];
#pragma unroll
    for (int mi = 0; mi < 4; ++mi)
#pragma unroll
        for (int ni = 0; ni < 4; ++ni) acc[mi][ni] = (f32x4){0.f, 0.f, 0.f, 0.f};

    for (int kc = 0; kc < 6; ++kc) {
        __syncthreads();
#pragma unroll
        for (int i = 0; i < 4; ++i) {
            const int row = i * 32 + g_row;
            if (m0 + row < 14700)
                load_lds16(Ag + (size_t)(m0 + row) * 384 + kc * 64 + src_g,
                           &Atile[(i * 256 + wv * 64) * 8]);
            load_lds16(Bg + (size_t)row * 384 + kc * 64 + src_g,
                       &Btile[(i * 256 + wv * 64) * 8]);
        }
        __syncthreads();
#pragma unroll
        for (int ks = 0; ks < 2; ++ks) {
            const int gsw = ((ks * 4 + hi) ^ swz) * 8;   // swizzled granule elem offset
            short8 af[4], bf[4];
#pragma unroll
            for (int mi = 0; mi < 4; ++mi)
                af[mi] = *(const short8*)(&Atile[(m0w + mi * 16 + l15) * 64 + gsw]);
#pragma unroll
            for (int ni = 0; ni < 4; ++ni)
                bf[ni] = *(const short8*)(&Btile[(n0w + ni * 16 + l15) * 64 + gsw]);
#pragma unroll
            for (int mi = 0; mi < 4; ++mi)
#pragma unroll
                for (int ni = 0; ni < 4; ++ni)
                    acc[mi][ni] = __builtin_amdgcn_mfma_f32_16x16x32_bf16(af[mi], bf[ni], acc[mi][ni], 0, 0, 0);
        }
    }

    // ---- epilogue: per-row max over this block's 128 cols (masked at class boundary) ----
    float rmax[4][4];
#pragma unroll
    for (int mi = 0; mi < 4; ++mi)
#pragma unroll
        for (int i = 0; i < 4; ++i) rmax[mi][i] = -3.0e38f;

    const int scol = s_loc + n0w + l15;
#pragma unroll
    for (int ni = 0; ni < 4; ++ni) {
        if (scol + ni * 16 < 980) {
#pragma unroll
            for (int mi = 0; mi < 4; ++mi)
#pragma unroll
                for (int i = 0; i < 4; ++i)
                    rmax[mi][i] = fmaxf(rmax[mi][i], acc[mi][ni][i]);
        }
    }
#pragma unroll
    for (int mi = 0; mi < 4; ++mi)
#pragma unroll
        for (int i = 0; i < 4; ++i) {
            float v = rmax[mi][i];
#pragma unroll
            for (int off = 1; off < 16; off <<= 1) v = fmaxf(v, __shfl_xor(v, off, 64));
            rmax[mi][i] = v;
        }
    if (l15 == 0) {
#pragma unroll
        for (int mi = 0; mi < 4; ++mi)
#pragma unroll
            for (int i = 0; i < 4; ++i)
                red[wv >> 1][m0w + mi * 16 + hi * 4 + i] = rmax[mi][i];
    }
    __syncthreads();
    if (tid < 128) {
        const int grow = m0 + tid;
        if (grow < 14700) {
            const float v = fmaxf(red[0][tid], red[1][tid]);
            atomicMax(&P[(size_t)(b * 5 + cls) * 14700 + grow], enc_f(v));
        }
    }
}

// ---------------- fused final: logits (mean over t of row maxima) | cls_logits ----------------
// blocks [0,188): logits (750 waves); [188,226): cls (150 waves)
__global__ void final_kernel(const unsigned* __restrict__ P,
                             const float* __restrict__ xq,
                             const float* __restrict__ proto,
                             float* __restrict__ out) {
    const int blk  = blockIdx.x;
    const int tid  = threadIdx.x;
    const int lane = tid & 63;
    const int wv   = tid >> 6;

    if (blk < 188) {                        // ---- logits ----
        const int gw = blk * 4 + wv;        // (b*75+q)*5+n
        if (gw >= 750) return;
        const int n  = gw % 5;
        const int bq = gw / 5;
        const int b  = bq / 75;
        const int q  = bq % 75;
        const unsigned* row = P + (size_t)(b * 5 + n) * 14700 + q * 196;
        float s = 0.f;
        for (int t = lane; t < 196; t += 64) s += dec_f(row[t]);
#pragma unroll
        for (int off = 1; off < 64; off <<= 1) s += __shfl_xor(s, off, 64);
        if (lane == 0) out[gw] = s * (1.0f / 196.0f);
    } else {                                // ---- cls_logits ----
        const int gw = (blk - 188) * 4 + wv;   // b*75+q
        if (gw >= 150) return;
        const float* row = xq + (size_t)gw * 384;
        float u[6];
        float ss = 0.f;
#pragma unroll
        for (int j = 0; j < 6; ++j) { u[j] = row[lane + 64 * j]; ss += u[j] * u[j]; }
#pragma unroll
        for (int off = 1; off < 64; off <<= 1) ss += __shfl_xor(ss, off, 64);
        const float scale = 1.0f / fmaxf(sqrtf(ss), 1e-12f);
#pragma unroll
        for (int j = 0; j < 6; ++j) u[j] *= scale;
        const int b = gw / 75;
        for (int n = 0; n < 5; ++n) {
            const float* p = proto + (size_t)(b * 5 + n) * 384;
            float d = 0.f;
#pragma unroll
            for (int j = 0; j < 6; ++j) d += u[j] * p[lane + 64 * j];
#pragma unroll
            for (int off = 1; off < 64; off <<= 1) d += __shfl_xor(d, off, 64);
            if (lane == 0) out[750 + gw * 5 + n] = 10.0f * d;
        }
    }
}

extern "C" void kernel_launch(void* const* d_in, const int* in_sizes, int n_in,
                              void* d_out, int out_size, void* d_ws, size_t ws_size,
                              hipStream_t stream) {
    const float* feat_shot  = (const float*)d_in[0];  // [2,5,5,196,384]
    const float* feat_query = (const float*)d_in[1];  // [2,75,196,384]
    const float* x_shot     = (const float*)d_in[2];  // [2,5,5,384]
    const float* x_query    = (const float*)d_in[3];  // [2,75,384]
    float* out = (float*)d_out;
    char* ws = (char*)d_ws;

    // ws layout (29.6 MiB total)
    __hip_bfloat16* fqn  = (__hip_bfloat16*)ws;                      // 22,579,200 B
    __hip_bfloat16* fsnp = (__hip_bfloat16*)(ws + 22579200);         //  7,864,320 B
    float*         proto = (float*)(ws + 30443520);                  //     15,360 B
    unsigned*      P     = (unsigned*)(ws + 30458880);               //    588,000 B

    prep_kernel<<<10488, 256, 0, stream>>>(feat_query, feat_shot, x_shot,
                                           fqn, fsnp, proto, P);
    gemm_kernel<<<2 * 115 * 40, 256, 0, stream>>>((const uint16_t*)fqn, (const uint16_t*)fsnp, P);
    final_kernel<<<226, 256, 0, stream>>>(P, x_query, proto, out);
}

// Round 4
// 210.700 us; speedup vs baseline: 4.4450x; 1.2055x over previous
//
#include <hip/hip_runtime.h>
#include <hip/hip_bf16.h>
#include <hip/hip_fp8.h>
#include <stdint.h>

// Shapes: b=2, n=5, k=5, q=75, t=196, c=384, s=k*t=980 (padded to 1024/class)
// M per b = 75*196 = 14700 (padded to 14720 = 115 tiles of 128)
// Outputs: logits [2,75,5] then cls_logits [2,75,5]
// Sim branch in OCP fp8-e4m3 via MX-scaled MFMA (scales=1.0); cls branch exact fp32.

typedef __attribute__((ext_vector_type(8))) int int8v;      // f8f6f4 A/B operand (32 fp8)
typedef __attribute__((ext_vector_type(4))) float f32x4;    // MFMA C/D frag

__device__ __forceinline__ void load_lds16(const void* g, void* l) {
    __builtin_amdgcn_global_load_lds(
        (const __attribute__((address_space(1))) unsigned int*)(uintptr_t)g,
        (__attribute__((address_space(3))) unsigned int*)(uintptr_t)l,
        16, 0, 0);
}

__device__ __forceinline__ unsigned enc_f(float f) {
    unsigned b = __float_as_uint(f);
    return (b & 0x80000000u) ? ~b : (b | 0x80000000u);
}
__device__ __forceinline__ float dec_f(unsigned u) {
    unsigned b = (u & 0x80000000u) ? (u & 0x7FFFFFFFu) : ~u;
    return __uint_as_float(b);
}

__device__ __forceinline__ unsigned to_fp8(float x) {
    __hip_fp8_e4m3 h(x);          // OCP e4m3fn on gfx950
    return (unsigned)h.__x;
}

// L2-normalize a 384-float row, emit fp8 bytes pair-packed as ushort (coalesced).
// Lane owns element pairs {2l,2l+1} + {2l+128,...} + {2l+256,...}.
__device__ __forceinline__ void norm_row_fp8(const float* __restrict__ row,
                                             uint16_t* __restrict__ o16, int lane) {
    float2 v[3];
    float ss = 0.f;
#pragma unroll
    for (int p = 0; p < 3; ++p) {
        v[p] = *(const float2*)(row + 2 * lane + 128 * p);
        ss += v[p].x * v[p].x + v[p].y * v[p].y;
    }
#pragma unroll
    for (int off = 1; off < 64; off <<= 1) ss += __shfl_xor(ss, off, 64);
    const float sc = 1.0f / fmaxf(sqrtf(ss), 1e-8f);
#pragma unroll
    for (int p = 0; p < 3; ++p) {
        const unsigned lo = to_fp8(v[p].x * sc);
        const unsigned hi = to_fp8(v[p].y * sc);
        o16[lane + 64 * p] = (uint16_t)(lo | (hi << 8));
    }
}

// ---------------- fused prep: norm_q | norm_s(padded) | proto | init_P ----------------
// blocks [0,7350): query tokens (4/block); [7350,9910): shot tokens padded (4/block);
// [9910,9913): proto; [9913,10488): init P.
__global__ void prep_kernel(const float* __restrict__ feat_query,
                            const float* __restrict__ feat_shot,
                            const float* __restrict__ x_shot,
                            uint16_t* __restrict__ fqn,
                            uint16_t* __restrict__ fsnp,
                            float* __restrict__ proto,
                            unsigned* __restrict__ P) {
    const int blk  = blockIdx.x;
    const int tid  = threadIdx.x;
    const int lane = tid & 63;
    const int wv   = tid >> 6;

    if (blk < 7350) {                       // ---- query token norm -> fp8 ----
        const int gw = blk * 4 + wv;        // 0..29399
        if (gw >= 29400) return;
        norm_row_fp8(feat_query + (size_t)gw * 384, fqn + (size_t)gw * 192, lane);
    } else if (blk < 9910) {                // ---- shot token norm -> fp8 padded layout ----
        const int gw = (blk - 7350) * 4 + wv;   // 0..10239
        if (gw >= 10240) return;
        const int bn = gw >> 10;
        const int s  = gw & 1023;
        uint16_t* o16 = fsnp + (size_t)gw * 192;
        if (s >= 980) {
#pragma unroll
            for (int p = 0; p < 3; ++p) o16[lane + 64 * p] = 0;
            return;
        }
        norm_row_fp8(feat_shot + ((size_t)bn * 980 + s) * 384, o16, lane);
    } else if (blk < 9913) {                // ---- proto = l2norm(mean_k x_shot), fp32 ----
        const int gw = (blk - 9910) * 4 + wv;
        if (gw >= 10) return;
        const float* base = x_shot + (size_t)gw * 5 * 384;
        float v[6];
        float ss = 0.f;
#pragma unroll
        for (int j = 0; j < 6; ++j) {
            float s = 0.f;
#pragma unroll
            for (int kk = 0; kk < 5; ++kk) s += base[kk * 384 + lane + 64 * j];
            s *= 0.2f;
            v[j] = s;
            ss += s * s;
        }
#pragma unroll
        for (int off = 1; off < 64; off <<= 1) ss += __shfl_xor(ss, off, 64);
        const float scale = 1.0f / fmaxf(sqrtf(ss), 1e-12f);
#pragma unroll
        for (int j = 0; j < 6; ++j) proto[(size_t)gw * 384 + lane + 64 * j] = v[j] * scale;
    } else {                                // ---- init P to encoded -inf (0) ----
        const int i = (blk - 9913) * 256 + tid;
        if (i < 147000) P[i] = 0u;
    }
}

// ---------------- batched fp8 GEMM + row-max: 128x128 tile, BK=128 elems (128 B) ----------------
// grid = 2 * 115 * 40. Rows in LDS are 128 B = 8 granules of 16 B; granule slot g holds
// source granule g ^ (r&7) (swizzle on the per-lane SOURCE address of global_load_lds).
// Frag reads address granules (2*hi)^ (l15&7) and (2*hi+1)^(l15&7) -> conflict-free
// (same math as the verified bf16 round-3 swizzle: rows were 128 B there too).
// MFMA: mfma_scale_f32_16x16x128_f8f6f4 with E8M0 scales = 0x7F (1.0) => plain fp8 matmul.
// Lane fragment layout: A[m=lane&15][k=(lane>>4)*32 + j], j=0..31 bytes; B analogous.
__global__ __launch_bounds__(256) void gemm_kernel(const uint8_t* __restrict__ fqn,
                                                   const uint8_t* __restrict__ fsnp,
                                                   unsigned* __restrict__ P) {
    __shared__ __align__(16) uint8_t Atile[128 * 128];   // 16 KB
    __shared__ __align__(16) uint8_t Btile[128 * 128];   // 16 KB
    __shared__ float red[2][128];                        //  1 KB

    const int bid = blockIdx.x;
    const int b   = bid / 4600;
    const int r   = bid % 4600;
    const int mt  = r / 40;
    const int st  = r % 40;
    const int m0  = mt * 128;          // row in [0,14720)
    const int s0  = st * 128;          // col in padded [0,5120)
    const int cls = s0 >> 10;          // class n
    const int s_loc = s0 & 1023;       // class-local col base

    const uint8_t* Ag = fqn  + (size_t)b * 14700 * 384;
    const uint8_t* Bg = fsnp + ((size_t)b * 5120 + s0) * 384;

    const int tid  = threadIdx.x;
    const int lane = tid & 63;
    const int wv   = tid >> 6;
    const int l15  = lane & 15;
    const int hi   = lane >> 4;
    const int m0w  = (wv & 1) * 64;
    const int n0w  = (wv >> 1) * 64;
    const int swz  = l15 & 7;

    // staging: row = i*32 + (tid>>3); LDS slot granule = tid&7;
    // source granule = (tid&7) ^ (row&7); 16 B granules over the 128 B K-chunk.
    const int g_row   = tid >> 3;                        // 0..31
    const int src_off = ((tid & 7) ^ (g_row & 7)) * 16;  // source byte offset in K-chunk

    f32x4 acc[4][4];
#pragma unroll
    for (int mi = 0; mi < 4; ++mi)
#pragma unroll
        for (int ni = 0; ni < 4; ++ni) acc[mi][ni] = (f32x4){0.f, 0.f, 0.f, 0.f};

#pragma unroll
    for (int kc = 0; kc < 3; ++kc) {
        __syncthreads();
#pragma unroll
        for (int i = 0; i < 4; ++i) {
            const int row = i * 32 + g_row;
            if (m0 + row < 14700)
                load_lds16(Ag + (size_t)(m0 + row) * 384 + kc * 128 + src_off,
                           &Atile[(i * 256 + wv * 64) * 16]);
            load_lds16(Bg + (size_t)row * 384 + kc * 128 + src_off,
                       &Btile[(i * 256 + wv * 64) * 16]);
        }
        __syncthreads();
        const int ga = ((2 * hi + 0) ^ swz) * 16;
        const int gb = ((2 * hi + 1) ^ swz) * 16;
        int8v af[4], bf[4];
#pragma unroll
        for (int mi = 0; mi < 4; ++mi) {
            const uint8_t* base = &Atile[(m0w + mi * 16 + l15) * 128];
            const uint4 x = *(const uint4*)(base + ga);
            const uint4 y = *(const uint4*)(base + gb);
            af[mi] = (int8v){(int)x.x, (int)x.y, (int)x.z, (int)x.w,
                             (int)y.x, (int)y.y, (int)y.z, (int)y.w};
        }
#pragma unroll
        for (int ni = 0; ni < 4; ++ni) {
            const uint8_t* base = &Btile[(n0w + ni * 16 + l15) * 128];
            const uint4 x = *(const uint4*)(base + ga);
            const uint4 y = *(const uint4*)(base + gb);
            bf[ni] = (int8v){(int)x.x, (int)x.y, (int)x.z, (int)x.w,
                             (int)y.x, (int)y.y, (int)y.z, (int)y.w};
        }
#pragma unroll
        for (int mi = 0; mi < 4; ++mi)
#pragma unroll
            for (int ni = 0; ni < 4; ++ni)
                acc[mi][ni] = __builtin_amdgcn_mfma_scale_f32_16x16x128_f8f6f4(
                    af[mi], bf[ni], acc[mi][ni],
                    0, 0,                    // cbsz=fp8(e4m3), blgp=fp8(e4m3)
                    0, 0x7F7F7F7F,           // scale_a opsel, scale_a = 1.0
                    0, 0x7F7F7F7F);          // scale_b opsel, scale_b = 1.0
    }

    // ---- epilogue: per-row max over this block's 128 cols (masked at class boundary) ----
    float rmax[4][4];
#pragma unroll
    for (int mi = 0; mi < 4; ++mi)
#pragma unroll
        for (int i = 0; i < 4; ++i) rmax[mi][i] = -3.0e38f;

    const int scol = s_loc + n0w + l15;
#pragma unroll
    for (int ni = 0; ni < 4; ++ni) {
        if (scol + ni * 16 < 980) {
#pragma unroll
            for (int mi = 0; mi < 4; ++mi)
#pragma unroll
                for (int i = 0; i < 4; ++i)
                    rmax[mi][i] = fmaxf(rmax[mi][i], acc[mi][ni][i]);
        }
    }
#pragma unroll
    for (int mi = 0; mi < 4; ++mi)
#pragma unroll
        for (int i = 0; i < 4; ++i) {
            float v = rmax[mi][i];
#pragma unroll
            for (int off = 1; off < 16; off <<= 1) v = fmaxf(v, __shfl_xor(v, off, 64));
            rmax[mi][i] = v;
        }
    if (l15 == 0) {
#pragma unroll
        for (int mi = 0; mi < 4; ++mi)
#pragma unroll
            for (int i = 0; i < 4; ++i)
                red[wv >> 1][m0w + mi * 16 + hi * 4 + i] = rmax[mi][i];
    }
    __syncthreads();
    if (tid < 128) {
        const int grow = m0 + tid;
        if (grow < 14700) {
            const float v = fmaxf(red[0][tid], red[1][tid]);
            atomicMax(&P[(size_t)(b * 5 + cls) * 14700 + grow], enc_f(v));
        }
    }
}

// ---------------- fused final: logits (mean over t of row maxima) | cls_logits ----------------
// blocks [0,188): logits (750 waves); [188,226): cls (150 waves)
__global__ void final_kernel(const unsigned* __restrict__ P,
                             const float* __restrict__ xq,
                             const float* __restrict__ proto,
                             float* __restrict__ out) {
    const int blk  = blockIdx.x;
    const int tid  = threadIdx.x;
    const int lane = tid & 63;
    const int wv   = tid >> 6;

    if (blk < 188) {                        // ---- logits ----
        const int gw = blk * 4 + wv;        // (b*75+q)*5+n
        if (gw >= 750) return;
        const int n  = gw % 5;
        const int bq = gw / 5;
        const int b  = bq / 75;
        const int q  = bq % 75;
        const unsigned* row = P + (size_t)(b * 5 + n) * 14700 + q * 196;
        float s = 0.f;
        for (int t = lane; t < 196; t += 64) s += dec_f(row[t]);
#pragma unroll
        for (int off = 1; off < 64; off <<= 1) s += __shfl_xor(s, off, 64);
        if (lane == 0) out[gw] = s * (1.0f / 196.0f);
    } else {                                // ---- cls_logits ----
        const int gw = (blk - 188) * 4 + wv;   // b*75+q
        if (gw >= 150) return;
        const float* row = xq + (size_t)gw * 384;
        float u[6];
        float ss = 0.f;
#pragma unroll
        for (int j = 0; j < 6; ++j) { u[j] = row[lane + 64 * j]; ss += u[j] * u[j]; }
#pragma unroll
        for (int off = 1; off < 64; off <<= 1) ss += __shfl_xor(ss, off, 64);
        const float scale = 1.0f / fmaxf(sqrtf(ss), 1e-12f);
#pragma unroll
        for (int j = 0; j < 6; ++j) u[j] *= scale;
        const int b = gw / 75;
        for (int n = 0; n < 5; ++n) {
            const float* p = proto + (size_t)(b * 5 + n) * 384;
            float d = 0.f;
#pragma unroll
            for (int j = 0; j < 6; ++j) d += u[j] * p[lane + 64 * j];
#pragma unroll
            for (int off = 1; off < 64; off <<= 1) d += __shfl_xor(d, off, 64);
            if (lane == 0) out[750 + gw * 5 + n] = 10.0f * d;
        }
    }
}

extern "C" void kernel_launch(void* const* d_in, const int* in_sizes, int n_in,
                              void* d_out, int out_size, void* d_ws, size_t ws_size,
                              hipStream_t stream) {
    const float* feat_shot  = (const float*)d_in[0];  // [2,5,5,196,384]
    const float* feat_query = (const float*)d_in[1];  // [2,75,196,384]
    const float* x_shot     = (const float*)d_in[2];  // [2,5,5,384]
    const float* x_query    = (const float*)d_in[3];  // [2,75,384]
    float* out = (float*)d_out;
    char* ws = (char*)d_ws;

    // ws layout (15.8 MiB total)
    uint8_t*  fqn   = (uint8_t*)ws;                     // 29400*384  = 11,289,600 B (fp8)
    uint8_t*  fsnp  = (uint8_t*)(ws + 11289600);        // 10240*384  =  3,932,160 B (fp8)
    float*    proto = (float*)(ws + 15221760);          //      3,840 f32
    unsigned* P     = (unsigned*)(ws + 15237120);       //    147,000 u32

    prep_kernel<<<10488, 256, 0, stream>>>(feat_query, feat_shot, x_shot,
                                           (uint16_t*)fqn, (uint16_t*)fsnp, proto, P);
    gemm_kernel<<<2 * 115 * 40, 256, 0, stream>>>(fqn, fsnp, P);
    final_kernel<<<226, 256, 0, stream>>>(P, x_query, proto, out);
}